// Round 1
// baseline (64.639 us; speedup 1.0000x reference)
//
#include <hip/hip_runtime.h>

// SurfEval: B=8, M=128, N=128, DIM=3 (ctrl has DIM+1=4 channels), P=Q=3, OUT=512
// ctrl_pts : (8, 128, 128, 4)  f32
// Nu_uv    : (512, 512, 4)     f32
// Nv_uv    : (512, 512, 4)     f32
// uspan_uv : (512, 512)        i32   values in [3, 128)
// vspan_uv : (512, 512)        i32
// out      : (8, 512, 512, 3)  f32   = sw[..., :3] / sw[..., 3]

#define OUTD 512
#define MD 128
#define ND 128

__global__ __launch_bounds__(256) void surfeval_kernel(
    const float* __restrict__ ctrl,
    const float* __restrict__ Nu,
    const float* __restrict__ Nv,
    const int* __restrict__ uspan,
    const int* __restrict__ vspan,
    float* __restrict__ out)
{
    const int tid = blockIdx.x * blockDim.x + threadIdx.x;  // (b*512 + u)*512 + v
    const int uv = tid & (OUTD * OUTD - 1);                 // u*512 + v
    const int b  = tid >> 18;

    const int us = uspan[uv];
    const int vs = vspan[uv];

    const float4 nu = reinterpret_cast<const float4*>(Nu)[uv];
    const float4 nv = reinterpret_cast<const float4*>(Nv)[uv];
    const float nuL[4] = {nu.x, nu.y, nu.z, nu.w};
    const float nvL[4] = {nv.x, nv.y, nv.z, nv.w};

    // patch base: ctrl[b][us-3][vs-3][.] as float4
    const float4* cp = reinterpret_cast<const float4*>(ctrl)
                     + ((b * MD + (us - 3)) * ND + (vs - 3));

    float ax = 0.f, ay = 0.f, az = 0.f, aw = 0.f;
    #pragma unroll
    for (int l = 0; l < 4; ++l) {
        const float4* row = cp + l * ND;
        #pragma unroll
        for (int r = 0; r < 4; ++r) {
            const float w = nuL[l] * nvL[r];
            const float4 c = row[r];
            ax = fmaf(w, c.x, ax);
            ay = fmaf(w, c.y, ay);
            az = fmaf(w, c.z, az);
            aw = fmaf(w, c.w, aw);
        }
    }

    const float inv = 1.0f / aw;
    float* o = out + (size_t)tid * 3;
    o[0] = ax * inv;
    o[1] = ay * inv;
    o[2] = az * inv;
}

extern "C" void kernel_launch(void* const* d_in, const int* in_sizes, int n_in,
                              void* d_out, int out_size, void* d_ws, size_t ws_size,
                              hipStream_t stream) {
    const float* ctrl  = (const float*)d_in[0];
    const float* Nu    = (const float*)d_in[1];
    const float* Nv    = (const float*)d_in[2];
    const int*   uspan = (const int*)d_in[3];
    const int*   vspan = (const int*)d_in[4];
    float* out = (float*)d_out;

    const int total = 8 * OUTD * OUTD;     // 2,097,152 threads
    const int block = 256;
    const int grid = total / block;        // 8192 blocks
    surfeval_kernel<<<grid, block, 0, stream>>>(ctrl, Nu, Nv, uspan, vspan, out);
}

// Round 2
// 63.142 us; speedup vs baseline: 1.0237x; 1.0237x over previous
//
#include <hip/hip_runtime.h>

// SurfEval: B=8, M=128, N=128, ctrl has 4 channels, P=Q=3, OUT=512
// ctrl_pts : (8, 128, 128, 4)  f32   (2 MB)
// Nu_uv    : (512, 512, 4)     f32
// Nv_uv    : (512, 512, 4)     f32
// uspan_uv : (512, 512)        i32   in [3,128)
// vspan_uv : (512, 512)        i32   in [3,128)
// out      : (8, 512, 512, 3)  f32   = sw[..., :3] / sw[..., 3]

#define OUTD 512
#define UVN  (OUTD * OUTD)   // 262144
#define MD   128
#define ND   128
#define BD   8

// ---------- transpose: ctrl (b,m,n,c4) -> ctrlT (m,n,b,c4) ----------
__global__ __launch_bounds__(256) void transpose_kernel(
    const float4* __restrict__ ctrl, float4* __restrict__ ctrlT)
{
    const int tid = blockIdx.x * blockDim.x + threadIdx.x;  // 0 .. 131071
    const int b   = tid & 7;
    const int mn  = tid >> 3;                 // m*128 + n
    ctrlT[tid] = ctrl[b * (MD * ND) + mn];    // writes fully coalesced
}

// ---------- main: one wave per (u,v), all 8 batches ----------
__global__ __launch_bounds__(256) void surfeval_t_kernel(
    const float4* __restrict__ ctrlT,
    const float4* __restrict__ Nu4,
    const float4* __restrict__ Nv4,
    const int* __restrict__ uspan,
    const int* __restrict__ vspan,
    float* __restrict__ out)
{
    const int lane = threadIdx.x & 63;
    const int uv   = blockIdx.x * 4 + (threadIdx.x >> 6);

    const int b  = lane & 7;
    const int r  = (lane >> 3) & 3;
    const int hi = lane >> 5;            // covers l = hi and l = 2+hi

    const int us = uspan[uv];
    const int vs = vspan[uv];
    const float4 nu = Nu4[uv];
    const float4 nv = Nv4[uv];

    const float nvr = (r == 0) ? nv.x : (r == 1) ? nv.y : (r == 2) ? nv.z : nv.w;
    const float nu0 = hi ? nu.y : nu.x;  // Nu[hi]
    const float nu1 = hi ? nu.w : nu.z;  // Nu[2+hi]

    const int base = (us - 3) * ND + (vs - 3);  // (m,n) corner, linear
    // element (l,r,b): ctrlT[(base + l*ND + r)*8 + b]
    // lanes 0..31 (hi=0): (r,b) sweep -> 512B contiguous per row. Fully coalesced.
    const float4 c0 = ctrlT[(size_t)(base + hi       * ND + r) * 8 + b];
    const float4 c1 = ctrlT[(size_t)(base + (2 + hi) * ND + r) * 8 + b];

    float sx = nvr * fmaf(nu0, c0.x, nu1 * c1.x);
    float sy = nvr * fmaf(nu0, c0.y, nu1 * c1.y);
    float sz = nvr * fmaf(nu0, c0.z, nu1 * c1.z);
    float sw = nvr * fmaf(nu0, c0.w, nu1 * c1.w);

    // reduce over lanes sharing b: bits 3,4 (r) and 5 (hi)
    #pragma unroll
    for (int off = 8; off <= 32; off <<= 1) {
        sx += __shfl_xor(sx, off, 64);
        sy += __shfl_xor(sy, off, 64);
        sz += __shfl_xor(sz, off, 64);
        sw += __shfl_xor(sw, off, 64);
    }
    // now every lane holds the full (4-comp) sum for its own b

    // 24 writer lanes: lane w -> batch wb = w/3, component w%3
    const int wb   = lane / 3;           // valid src lane for shfl even when >=8
    const int comp = lane - wb * 3;
    const float gx = __shfl(sx, wb, 64);
    const float gy = __shfl(sy, wb, 64);
    const float gz = __shfl(sz, wb, 64);
    const float gw = __shfl(sw, wb, 64);
    if (lane < 24) {
        const float val = (comp == 0) ? gx : (comp == 1) ? gy : gz;
        out[(size_t)wb * (UVN * 3) + (size_t)uv * 3 + comp] = val / gw;
    }
}

// ---------- fallback (verified round-1 kernel) ----------
__global__ __launch_bounds__(256) void surfeval_naive_kernel(
    const float* __restrict__ ctrl,
    const float* __restrict__ Nu,
    const float* __restrict__ Nv,
    const int* __restrict__ uspan,
    const int* __restrict__ vspan,
    float* __restrict__ out)
{
    const int tid = blockIdx.x * blockDim.x + threadIdx.x;
    const int uv = tid & (UVN - 1);
    const int b  = tid >> 18;

    const int us = uspan[uv];
    const int vs = vspan[uv];
    const float4 nu = reinterpret_cast<const float4*>(Nu)[uv];
    const float4 nv = reinterpret_cast<const float4*>(Nv)[uv];
    const float nuL[4] = {nu.x, nu.y, nu.z, nu.w};
    const float nvL[4] = {nv.x, nv.y, nv.z, nv.w};

    const float4* cp = reinterpret_cast<const float4*>(ctrl)
                     + ((b * MD + (us - 3)) * ND + (vs - 3));
    float ax = 0.f, ay = 0.f, az = 0.f, aw = 0.f;
    #pragma unroll
    for (int l = 0; l < 4; ++l) {
        const float4* row = cp + l * ND;
        #pragma unroll
        for (int r = 0; r < 4; ++r) {
            const float w = nuL[l] * nvL[r];
            const float4 c = row[r];
            ax = fmaf(w, c.x, ax); ay = fmaf(w, c.y, ay);
            az = fmaf(w, c.z, az); aw = fmaf(w, c.w, aw);
        }
    }
    const float inv = 1.0f / aw;
    float* o = out + (size_t)tid * 3;
    o[0] = ax * inv; o[1] = ay * inv; o[2] = az * inv;
}

extern "C" void kernel_launch(void* const* d_in, const int* in_sizes, int n_in,
                              void* d_out, int out_size, void* d_ws, size_t ws_size,
                              hipStream_t stream) {
    const float* ctrl  = (const float*)d_in[0];
    const float* Nu    = (const float*)d_in[1];
    const float* Nv    = (const float*)d_in[2];
    const int*   uspan = (const int*)d_in[3];
    const int*   vspan = (const int*)d_in[4];
    float* out = (float*)d_out;

    const size_t ctrlT_bytes = (size_t)MD * ND * BD * 4 * sizeof(float);  // 2 MB

    if (ws_size >= ctrlT_bytes) {
        float4* ctrlT = (float4*)d_ws;
        transpose_kernel<<<(MD * ND * BD) / 256, 256, 0, stream>>>(
            (const float4*)ctrl, ctrlT);
        surfeval_t_kernel<<<UVN / 4, 256, 0, stream>>>(
            ctrlT, (const float4*)Nu, (const float4*)Nv, uspan, vspan, out);
    } else {
        const int total = BD * UVN;
        surfeval_naive_kernel<<<total / 256, 256, 0, stream>>>(
            ctrl, Nu, Nv, uspan, vspan, out);
    }
}

// Round 3
// 35.736 us; speedup vs baseline: 1.8088x; 1.7669x over previous
//
#include <hip/hip_runtime.h>

// SurfEval: B=8, M=128, N=128, ctrl has 4 channels, P=Q=3, OUT=512
// ctrl_pts : (8, 128, 128, 4)  f32   (2 MB)
// Nu_uv    : (512, 512, 4)     f32
// Nv_uv    : (512, 512, 4)     f32
// uspan_uv : (512, 512)        i32   in [3,128)
// vspan_uv : (512, 512)        i32   in [3,128)
// out      : (8, 512, 512, 3)  f32   = sw[..., :3] / sw[..., 3]

#define OUTD 512
#define UVN  (OUTD * OUTD)   // 262144
#define MD   128
#define ND   128
#define BD   8

// ---------- transpose: ctrl (b,m,n,c4) -> ctrlT (m,n,b,c4) ----------
__global__ __launch_bounds__(256) void transpose_kernel(
    const float4* __restrict__ ctrl, float4* __restrict__ ctrlT)
{
    const int tid = blockIdx.x * blockDim.x + threadIdx.x;  // 0 .. 131071
    const int b   = tid & 7;
    const int mn  = tid >> 3;                 // m*128 + n
    ctrlT[tid] = ctrl[b * (MD * ND) + mn];    // writes fully coalesced
}

// ---------- main: thread = (uv, b); 8 lanes share uv -> 128B coalesced chunks
__global__ __launch_bounds__(256) void surfeval_e_kernel(
    const float4* __restrict__ ctrlT,
    const float4* __restrict__ Nu4,
    const float4* __restrict__ Nv4,
    const int* __restrict__ uspan,
    const int* __restrict__ vspan,
    float* __restrict__ out)
{
    const int t  = blockIdx.x * blockDim.x + threadIdx.x;  // 0 .. 2M-1
    const int b  = t & 7;
    const int uv = t >> 3;

    const int us = uspan[uv];
    const int vs = vspan[uv];
    const float4 nu = Nu4[uv];
    const float4 nv = Nv4[uv];
    const float nuL[4] = {nu.x, nu.y, nu.z, nu.w};
    const float nvL[4] = {nv.x, nv.y, nv.z, nv.w};

    // element (l,r): ctrlT[((us-3+l)*ND + (vs-3+r))*8 + b]
    // For fixed (l,r), lanes b=0..7 of one uv read 128B contiguous, 128B-aligned.
    const float4* cp = ctrlT + ((size_t)((us - 3) * ND + (vs - 3)) * 8 + b);

    float ax = 0.f, ay = 0.f, az = 0.f, aw = 0.f;
    #pragma unroll
    for (int l = 0; l < 4; ++l) {
        #pragma unroll
        for (int r = 0; r < 4; ++r) {
            const float w = nuL[l] * nvL[r];
            const float4 c = cp[(l * ND + r) * 8];
            ax = fmaf(w, c.x, ax);
            ay = fmaf(w, c.y, ay);
            az = fmaf(w, c.z, az);
            aw = fmaf(w, c.w, aw);
        }
    }

    const float inv = 1.0f / aw;
    float* o = out + ((size_t)b * UVN + uv) * 3;
    o[0] = ax * inv;
    o[1] = ay * inv;
    o[2] = az * inv;
}

// ---------- fallback (verified round-1 kernel, no workspace needed) ----------
__global__ __launch_bounds__(256) void surfeval_naive_kernel(
    const float* __restrict__ ctrl,
    const float* __restrict__ Nu,
    const float* __restrict__ Nv,
    const int* __restrict__ uspan,
    const int* __restrict__ vspan,
    float* __restrict__ out)
{
    const int tid = blockIdx.x * blockDim.x + threadIdx.x;
    const int uv = tid & (UVN - 1);
    const int b  = tid >> 18;

    const int us = uspan[uv];
    const int vs = vspan[uv];
    const float4 nu = reinterpret_cast<const float4*>(Nu)[uv];
    const float4 nv = reinterpret_cast<const float4*>(Nv)[uv];
    const float nuL[4] = {nu.x, nu.y, nu.z, nu.w};
    const float nvL[4] = {nv.x, nv.y, nv.z, nv.w};

    const float4* cp = reinterpret_cast<const float4*>(ctrl)
                     + ((b * MD + (us - 3)) * ND + (vs - 3));
    float ax = 0.f, ay = 0.f, az = 0.f, aw = 0.f;
    #pragma unroll
    for (int l = 0; l < 4; ++l) {
        const float4* row = cp + l * ND;
        #pragma unroll
        for (int r = 0; r < 4; ++r) {
            const float w = nuL[l] * nvL[r];
            const float4 c = row[r];
            ax = fmaf(w, c.x, ax); ay = fmaf(w, c.y, ay);
            az = fmaf(w, c.z, az); aw = fmaf(w, c.w, aw);
        }
    }
    const float inv = 1.0f / aw;
    float* o = out + (size_t)tid * 3;
    o[0] = ax * inv; o[1] = ay * inv; o[2] = az * inv;
}

extern "C" void kernel_launch(void* const* d_in, const int* in_sizes, int n_in,
                              void* d_out, int out_size, void* d_ws, size_t ws_size,
                              hipStream_t stream) {
    const float* ctrl  = (const float*)d_in[0];
    const float* Nu    = (const float*)d_in[1];
    const float* Nv    = (const float*)d_in[2];
    const int*   uspan = (const int*)d_in[3];
    const int*   vspan = (const int*)d_in[4];
    float* out = (float*)d_out;

    const size_t ctrlT_bytes = (size_t)MD * ND * BD * 4 * sizeof(float);  // 2 MB

    if (ws_size >= ctrlT_bytes) {
        float4* ctrlT = (float4*)d_ws;
        transpose_kernel<<<(MD * ND * BD) / 256, 256, 0, stream>>>(
            (const float4*)ctrl, ctrlT);
        const int total = BD * UVN;            // 2,097,152 threads
        surfeval_e_kernel<<<total / 256, 256, 0, stream>>>(
            ctrlT, (const float4*)Nu, (const float4*)Nv, uspan, vspan, out);
    } else {
        const int total = BD * UVN;
        surfeval_naive_kernel<<<total / 256, 256, 0, stream>>>(
            ctrl, Nu, Nv, uspan, vspan, out);
    }
}

// Round 4
// 33.220 us; speedup vs baseline: 1.9458x; 1.0757x over previous
//
#include <hip/hip_runtime.h>

// SurfEval: B=8, M=128, N=128, ctrl has 4 channels, P=Q=3, OUT=512
// ctrl_pts : (8, 128, 128, 4)  f32   (2 MB)
// Nu_uv    : (512, 512, 4)     f32
// Nv_uv    : (512, 512, 4)     f32
// uspan_uv : (512, 512)        i32   in [3,128)
// vspan_uv : (512, 512)        i32   in [3,128)
// out      : (8, 512, 512, 3)  f32   = sw[..., :3] / sw[..., 3]

#define OUTD 512
#define UVN  (OUTD * OUTD)   // 262144
#define MD   128
#define ND   128
#define BD   8

// ---------- transpose: ctrl (b,m,n,c4) -> ctrlT (m,n,b,c4) ----------
__global__ __launch_bounds__(256) void transpose_kernel(
    const float4* __restrict__ ctrl, float4* __restrict__ ctrlT)
{
    const int tid = blockIdx.x * blockDim.x + threadIdx.x;  // 0 .. 131071
    const int b   = tid & 7;
    const int mn  = tid >> 3;                 // m*128 + n
    ctrlT[tid] = ctrl[b * (MD * ND) + mn];    // writes fully coalesced
}

// ---------- main: thread = (uv, b); 8 lanes share uv -> 128B coalesced chunks
// Block = 256 threads = 32 uv x 8 b. LDS reorder for coalesced stores.
__global__ __launch_bounds__(256) void surfeval_e_kernel(
    const float4* __restrict__ ctrlT,
    const float4* __restrict__ Nu4,
    const float4* __restrict__ Nv4,
    const int* __restrict__ uspan,
    const int* __restrict__ vspan,
    float* __restrict__ out)
{
    __shared__ float res[BD * 32 * 3];   // [b][uvLocal][c] -> 3 KB

    const int tidx = threadIdx.x;
    const int b    = tidx & 7;
    const int uvL  = tidx >> 3;                    // 0..31
    const int uv   = blockIdx.x * 32 + uvL;

    const int us = uspan[uv];
    const int vs = vspan[uv];
    const float4 nu = Nu4[uv];
    const float4 nv = Nv4[uv];
    const float nuL[4] = {nu.x, nu.y, nu.z, nu.w};
    const float nvL[4] = {nv.x, nv.y, nv.z, nv.w};

    // element (l,r): ctrlT[((us-3+l)*ND + (vs-3+r))*8 + b]
    // For fixed (l,r), the 8 lanes sharing uv read 128B contiguous & aligned.
    const float4* cp = ctrlT + ((size_t)((us - 3) * ND + (vs - 3)) * 8 + b);

    // ---- load phase: 16 independent global_load_dwordx4, imm offsets per row
    float4 c[4][4];
    #pragma unroll
    for (int l = 0; l < 4; ++l) {
        const float4* row = cp + l * (ND * 8);   // row base; r offsets 0/128/256/384 B
        #pragma unroll
        for (int r = 0; r < 4; ++r)
            c[l][r] = row[r * 8];
    }

    // ---- compute phase
    float ax = 0.f, ay = 0.f, az = 0.f, aw = 0.f;
    #pragma unroll
    for (int l = 0; l < 4; ++l) {
        #pragma unroll
        for (int r = 0; r < 4; ++r) {
            const float w = nuL[l] * nvL[r];
            ax = fmaf(w, c[l][r].x, ax);
            ay = fmaf(w, c[l][r].y, ay);
            az = fmaf(w, c[l][r].z, az);
            aw = fmaf(w, c[l][r].w, aw);
        }
    }

    const float inv = 1.0f / aw;
    float* rp = &res[(b * 32 + uvL) * 3];
    rp[0] = ax * inv;
    rp[1] = ay * inv;
    rp[2] = az * inv;

    __syncthreads();

    // ---- store phase: 192 threads emit coalesced dwordx4.
    // Per b: 32 uv x 3 floats = 384 B contiguous = 24 float4 stores.
    if (tidx < 192) {
        const int rb = tidx / 24;          // batch
        const int k  = tidx - rb * 24;     // which float4 within the 384B run
        const float4 v = reinterpret_cast<const float4*>(&res[rb * 96])[k];
        float* dst = out + (size_t)rb * (UVN * 3) + (size_t)blockIdx.x * 96 + k * 4;
        *reinterpret_cast<float4*>(dst) = v;
    }
}

// ---------- fallback (verified round-1 kernel, no workspace needed) ----------
__global__ __launch_bounds__(256) void surfeval_naive_kernel(
    const float* __restrict__ ctrl,
    const float* __restrict__ Nu,
    const float* __restrict__ Nv,
    const int* __restrict__ uspan,
    const int* __restrict__ vspan,
    float* __restrict__ out)
{
    const int tid = blockIdx.x * blockDim.x + threadIdx.x;
    const int uv = tid & (UVN - 1);
    const int b  = tid >> 18;

    const int us = uspan[uv];
    const int vs = vspan[uv];
    const float4 nu = reinterpret_cast<const float4*>(Nu)[uv];
    const float4 nv = reinterpret_cast<const float4*>(Nv)[uv];
    const float nuL[4] = {nu.x, nu.y, nu.z, nu.w};
    const float nvL[4] = {nv.x, nv.y, nv.z, nv.w};

    const float4* cp = reinterpret_cast<const float4*>(ctrl)
                     + ((b * MD + (us - 3)) * ND + (vs - 3));
    float ax = 0.f, ay = 0.f, az = 0.f, aw = 0.f;
    #pragma unroll
    for (int l = 0; l < 4; ++l) {
        const float4* row = cp + l * ND;
        #pragma unroll
        for (int r = 0; r < 4; ++r) {
            const float w = nuL[l] * nvL[r];
            const float4 cc = row[r];
            ax = fmaf(w, cc.x, ax); ay = fmaf(w, cc.y, ay);
            az = fmaf(w, cc.z, az); aw = fmaf(w, cc.w, aw);
        }
    }
    const float inv = 1.0f / aw;
    float* o = out + (size_t)tid * 3;
    o[0] = ax * inv; o[1] = ay * inv; o[2] = az * inv;
}

extern "C" void kernel_launch(void* const* d_in, const int* in_sizes, int n_in,
                              void* d_out, int out_size, void* d_ws, size_t ws_size,
                              hipStream_t stream) {
    const float* ctrl  = (const float*)d_in[0];
    const float* Nu    = (const float*)d_in[1];
    const float* Nv    = (const float*)d_in[2];
    const int*   uspan = (const int*)d_in[3];
    const int*   vspan = (const int*)d_in[4];
    float* out = (float*)d_out;

    const size_t ctrlT_bytes = (size_t)MD * ND * BD * 4 * sizeof(float);  // 2 MB

    if (ws_size >= ctrlT_bytes) {
        float4* ctrlT = (float4*)d_ws;
        transpose_kernel<<<(MD * ND * BD) / 256, 256, 0, stream>>>(
            (const float4*)ctrl, ctrlT);
        surfeval_e_kernel<<<UVN / 32, 256, 0, stream>>>(
            ctrlT, (const float4*)Nu, (const float4*)Nv, uspan, vspan, out);
    } else {
        const int total = BD * UVN;
        surfeval_naive_kernel<<<total / 256, 256, 0, stream>>>(
            ctrl, Nu, Nv, uspan, vspan, out);
    }
}

// Round 5
// 31.153 us; speedup vs baseline: 2.0749x; 1.0663x over previous
//
#include <hip/hip_runtime.h>
#include <hip/hip_fp16.h>

// SurfEval: B=8, M=128, N=128, ctrl has 4 channels, P=Q=3, OUT=512
// ctrl_pts : (8, 128, 128, 4)  f32   (2 MB)
// Nu_uv    : (512, 512, 4)     f32
// Nv_uv    : (512, 512, 4)     f32
// uspan_uv : (512, 512)        i32   in [3,128)
// vspan_uv : (512, 512)        i32   in [3,128)
// out      : (8, 512, 512, 3)  f32   = sw[..., :3] / sw[..., 3]
//
// Staged layout: ctrlH[(m*128+n)*8 + b] as half4 (8 B)  -> 1 MB in d_ws.
// For fixed (l,r), the 8 lanes sharing a uv read one fully-used 64 B line.

#define OUTD 512
#define UVN  (OUTD * OUTD)   // 262144
#define MD   128
#define ND   128
#define BD   8

// ---------- transpose+convert: ctrl (b,m,n,4f32) -> ctrlH (m,n,b,4f16) ----------
__global__ __launch_bounds__(256) void transpose_h_kernel(
    const float4* __restrict__ ctrl, ushort4* __restrict__ ctrlH)
{
    const int tid = blockIdx.x * blockDim.x + threadIdx.x;  // 0 .. 131071
    const int b   = tid & 7;
    const int mn  = tid >> 3;                 // m*128 + n
    const float4 c = ctrl[b * (MD * ND) + mn];
    ushort4 h;
    h.x = __half_as_ushort(__float2half(c.x));
    h.y = __half_as_ushort(__float2half(c.y));
    h.z = __half_as_ushort(__float2half(c.z));
    h.w = __half_as_ushort(__float2half(c.w));
    ctrlH[tid] = h;                           // coalesced 8B stores
}

// ---------- main: thread = (uv, b); fp16 patch gather, f32 accumulate ----------
__global__ __launch_bounds__(256) void surfeval_h_kernel(
    const uint2* __restrict__ ctrlH,
    const float4* __restrict__ Nu4,
    const float4* __restrict__ Nv4,
    const int* __restrict__ uspan,
    const int* __restrict__ vspan,
    float* __restrict__ out)
{
    __shared__ float res[BD * 32 * 3];   // [b][uvLocal][c] -> 3 KB

    const int tidx = threadIdx.x;
    const int b    = tidx & 7;
    const int uvL  = tidx >> 3;                    // 0..31
    const int uv   = blockIdx.x * 32 + uvL;

    const int us = uspan[uv];
    const int vs = vspan[uv];
    const float4 nu = Nu4[uv];
    const float4 nv = Nv4[uv];
    const float nuL[4] = {nu.x, nu.y, nu.z, nu.w};
    const float nvL[4] = {nv.x, nv.y, nv.z, nv.w};

    // element (l,r): ctrlH[((us-3+l)*ND + (vs-3+r))*8 + b]  (8 B each)
    const uint2* cp = ctrlH + ((size_t)((us - 3) * ND + (vs - 3)) * 8 + b);

    // ---- load phase: 16 independent global_load_dwordx2, imm offsets per row
    uint2 c[4][4];
    #pragma unroll
    for (int l = 0; l < 4; ++l) {
        const uint2* row = cp + l * (ND * 8);   // r offsets: 0/64/128/192 B
        #pragma unroll
        for (int r = 0; r < 4; ++r)
            c[l][r] = row[r * 8];
    }

    // ---- compute phase (f32 accumulate)
    float ax = 0.f, ay = 0.f, az = 0.f, aw = 0.f;
    #pragma unroll
    for (int l = 0; l < 4; ++l) {
        #pragma unroll
        for (int r = 0; r < 4; ++r) {
            const float w = nuL[l] * nvL[r];
            const __half2 h01 = *reinterpret_cast<const __half2*>(&c[l][r].x);
            const __half2 h23 = *reinterpret_cast<const __half2*>(&c[l][r].y);
            const float2 xy = __half22float2(h01);
            const float2 zw = __half22float2(h23);
            ax = fmaf(w, xy.x, ax);
            ay = fmaf(w, xy.y, ay);
            az = fmaf(w, zw.x, az);
            aw = fmaf(w, zw.y, aw);
        }
    }

    const float inv = 1.0f / aw;
    float* rp = &res[(b * 32 + uvL) * 3];
    rp[0] = ax * inv;
    rp[1] = ay * inv;
    rp[2] = az * inv;

    __syncthreads();

    // ---- store phase: 192 threads emit coalesced dwordx4.
    // Per b: 32 uv x 3 floats = 384 B contiguous = 24 float4 stores.
    if (tidx < 192) {
        const int rb = tidx / 24;          // batch
        const int k  = tidx - rb * 24;     // which float4 within the 384B run
        const float4 v = reinterpret_cast<const float4*>(&res[rb * 96])[k];
        float* dst = out + (size_t)rb * (UVN * 3) + (size_t)blockIdx.x * 96 + k * 4;
        *reinterpret_cast<float4*>(dst) = v;
    }
}

// ---------- fallback (verified round-1 kernel, no workspace needed) ----------
__global__ __launch_bounds__(256) void surfeval_naive_kernel(
    const float* __restrict__ ctrl,
    const float* __restrict__ Nu,
    const float* __restrict__ Nv,
    const int* __restrict__ uspan,
    const int* __restrict__ vspan,
    float* __restrict__ out)
{
    const int tid = blockIdx.x * blockDim.x + threadIdx.x;
    const int uv = tid & (UVN - 1);
    const int b  = tid >> 18;

    const int us = uspan[uv];
    const int vs = vspan[uv];
    const float4 nu = reinterpret_cast<const float4*>(Nu)[uv];
    const float4 nv = reinterpret_cast<const float4*>(Nv)[uv];
    const float nuL[4] = {nu.x, nu.y, nu.z, nu.w};
    const float nvL[4] = {nv.x, nv.y, nv.z, nv.w};

    const float4* cp = reinterpret_cast<const float4*>(ctrl)
                     + ((b * MD + (us - 3)) * ND + (vs - 3));
    float ax = 0.f, ay = 0.f, az = 0.f, aw = 0.f;
    #pragma unroll
    for (int l = 0; l < 4; ++l) {
        const float4* row = cp + l * ND;
        #pragma unroll
        for (int r = 0; r < 4; ++r) {
            const float w = nuL[l] * nvL[r];
            const float4 cc = row[r];
            ax = fmaf(w, cc.x, ax); ay = fmaf(w, cc.y, ay);
            az = fmaf(w, cc.z, az); aw = fmaf(w, cc.w, aw);
        }
    }
    const float inv = 1.0f / aw;
    float* o = out + (size_t)tid * 3;
    o[0] = ax * inv; o[1] = ay * inv; o[2] = az * inv;
}

extern "C" void kernel_launch(void* const* d_in, const int* in_sizes, int n_in,
                              void* d_out, int out_size, void* d_ws, size_t ws_size,
                              hipStream_t stream) {
    const float* ctrl  = (const float*)d_in[0];
    const float* Nu    = (const float*)d_in[1];
    const float* Nv    = (const float*)d_in[2];
    const int*   uspan = (const int*)d_in[3];
    const int*   vspan = (const int*)d_in[4];
    float* out = (float*)d_out;

    const size_t ctrlH_bytes = (size_t)MD * ND * BD * 4 * sizeof(unsigned short); // 1 MB

    if (ws_size >= ctrlH_bytes) {
        ushort4* ctrlH = (ushort4*)d_ws;
        transpose_h_kernel<<<(MD * ND * BD) / 256, 256, 0, stream>>>(
            (const float4*)ctrl, ctrlH);
        surfeval_h_kernel<<<UVN / 32, 256, 0, stream>>>(
            (const uint2*)ctrlH, (const float4*)Nu, (const float4*)Nv,
            uspan, vspan, out);
    } else {
        const int total = BD * UVN;
        surfeval_naive_kernel<<<total / 256, 256, 0, stream>>>(
            ctrl, Nu, Nv, uspan, vspan, out);
    }
}